// Round 6
// baseline (318.008 us; speedup 1.0000x reference)
//
#include <hip/hip_runtime.h>
#include <hip/hip_bf16.h>

// GIN 2-layer forward — R6: gather fused into the MFMA layer kernels.
//
//   CSR build: memset/degree -> block_sum -> scan_partials -> scan_blocks -> fill
//   x_bf = bf16(x); w{1,2,3}t = bf16(w^T) (one merged transpose launch)
//   layer1_fused: [gather x_bf -> LDS] -> relu(.@w1+b1) -> LDS -> relu(.@w2+b2) -> h1
//   layer2_fused: [gather h1  -> LDS] -> relu(.@w3+b3) -> LDS -> log_softmax head -> out

typedef __attribute__((ext_vector_type(8))) short bf16x8;
typedef __attribute__((ext_vector_type(4))) float f32x4;

static __device__ __forceinline__ unsigned short f2bf(float f) {
    unsigned int u = __float_as_uint(f);
    unsigned int r = (u + 0x7fffu + ((u >> 16) & 1u)) >> 16;
    return (unsigned short)r;
}
static __device__ __forceinline__ float bf2f(unsigned short s) {
    return __uint_as_float(((unsigned int)s) << 16);
}
static __device__ __forceinline__ float bflo(unsigned int u) {
    return __uint_as_float(u << 16);
}
static __device__ __forceinline__ float bfhi(unsigned int u) {
    return __uint_as_float(u & 0xffff0000u);
}

#define S1 136   // 128 + 8 pad (bf16 elems)
#define S2 264   // 256 + 8 pad

// ---------------- CSR build ----------------
__global__ __launch_bounds__(256) void degree_kernel(
    const int* __restrict__ dst, int* __restrict__ deg, int E)
{
    const int e = blockIdx.x * 256 + threadIdx.x;
    if (e < E) atomicAdd(&deg[dst[e]], 1);
}

__global__ __launch_bounds__(256) void block_sum_kernel(
    const int* __restrict__ deg, int* __restrict__ bsum, int M)
{
    const int b = blockIdx.x, t = threadIdx.x;
    const int idx = b * 1024 + t * 4;
    int s = 0;
    if (idx + 3 < M) {
        const int4 v = *(const int4*)(deg + idx);
        s = v.x + v.y + v.z + v.w;
    } else {
        #pragma unroll
        for (int i = 0; i < 4; ++i) if (idx + i < M) s += deg[idx + i];
    }
    #pragma unroll
    for (int off = 32; off > 0; off >>= 1) s += __shfl_down(s, off);
    __shared__ int ws[4];
    if ((t & 63) == 0) ws[t >> 6] = s;
    __syncthreads();
    if (t == 0) bsum[b] = ws[0] + ws[1] + ws[2] + ws[3];
}

__global__ __launch_bounds__(64) void scan_partials_kernel(
    const int* __restrict__ bsum, int* __restrict__ boff, int nB)
{
    const int t = threadIdx.x;
    const int v = (t < nB) ? bsum[t] : 0;
    int inc = v;
    #pragma unroll
    for (int off = 1; off < 64; off <<= 1) {
        const int u = __shfl_up(inc, off);
        if (t >= off) inc += u;
    }
    if (t < nB) boff[t] = inc - v;
}

__global__ __launch_bounds__(256) void scan_blocks_kernel(
    const int* __restrict__ deg, const int* __restrict__ boff,
    int* __restrict__ rowptr, int* __restrict__ cur, int M, int E)
{
    const int b = blockIdx.x, t = threadIdx.x;
    const int idx = b * 1024 + t * 4;
    int4 d = make_int4(0, 0, 0, 0);
    if (idx + 3 < M) {
        d = *(const int4*)(deg + idx);
    } else {
        if (idx + 0 < M) d.x = deg[idx + 0];
        if (idx + 1 < M) d.y = deg[idx + 1];
        if (idx + 2 < M) d.z = deg[idx + 2];
        if (idx + 3 < M) d.w = deg[idx + 3];
    }
    const int tot = d.x + d.y + d.z + d.w;
    const int lane = t & 63, wid = t >> 6;
    int inc = tot;
    #pragma unroll
    for (int off = 1; off < 64; off <<= 1) {
        const int u = __shfl_up(inc, off);
        if (lane >= off) inc += u;
    }
    __shared__ int wsum[4];
    if (lane == 63) wsum[wid] = inc;
    __syncthreads();
    int woff = 0;
    #pragma unroll
    for (int w = 0; w < 4; ++w) if (w < wid) woff += wsum[w];
    int p = boff[b] + woff + (inc - tot);
    if (idx + 0 < M) { rowptr[idx + 0] = p; cur[idx + 0] = p; } p += d.x;
    if (idx + 1 < M) { rowptr[idx + 1] = p; cur[idx + 1] = p; } p += d.y;
    if (idx + 2 < M) { rowptr[idx + 2] = p; cur[idx + 2] = p; } p += d.z;
    if (idx + 3 < M) { rowptr[idx + 3] = p; cur[idx + 3] = p; }
    if (b == 0 && t == 0) rowptr[M] = E;
}

__global__ __launch_bounds__(256) void fill_kernel(
    const int* __restrict__ src, const int* __restrict__ dst,
    int* __restrict__ cur, int* __restrict__ srcs, int E)
{
    const int e = blockIdx.x * 256 + threadIdx.x;
    if (e >= E) return;
    const int p = atomicAdd(&cur[dst[e]], 1);
    srcs[p] = src[e];
}

// ---------------- converts ----------------
__global__ __launch_bounds__(256) void cvt_bf16_kernel(
    const float* __restrict__ in, short* __restrict__ outb, int n4)
{
    const int i = (blockIdx.x * 256 + threadIdx.x);
    if (i >= n4) return;
    const float4 v = *(const float4*)(in + (size_t)i * 4);
    ushort4 o;
    o.x = f2bf(v.x); o.y = f2bf(v.y); o.z = f2bf(v.z); o.w = f2bf(v.w);
    *(ushort4*)(outb + (size_t)i * 4) = o;
}

// merged 3-way transpose: out[n][k] (bf16, padded) = in[k][n] (fp32)
__global__ __launch_bounds__(256) void transpose_cvt3_kernel(
    const float* __restrict__ w1, const float* __restrict__ w2, const float* __restrict__ w3,
    short* __restrict__ w1t, short* __restrict__ w2t, short* __restrict__ w3t)
{
    const int z = blockIdx.z;
    const float* in; short* outb; int K, ostride;
    if (z == 0)      { in = w1; outb = w1t; K = 128; ostride = S1; }
    else if (z == 1) { in = w2; outb = w2t; K = 256; ostride = S2; }
    else             { in = w3; outb = w3t; K = 256; ostride = S2; }
    const int N = 256;
    const int k0 = blockIdx.x * 32;
    if (k0 >= K) return;
    const int n0 = blockIdx.y * 32;
    __shared__ float tile[32][33];
    const int tx = threadIdx.x & 31;
    const int ty = threadIdx.x >> 5;   // 0..7
    #pragma unroll
    for (int i = 0; i < 4; ++i)
        tile[ty + 8 * i][tx] = in[(size_t)(k0 + ty + 8 * i) * N + n0 + tx];
    __syncthreads();
    #pragma unroll
    for (int i = 0; i < 4; ++i)
        outb[(size_t)(n0 + ty + 8 * i) * ostride + k0 + tx] = (short)f2bf(tile[tx][ty + 8 * i]);
}

// ---------------- layer1: h1 = relu(relu((x+agg(x))@w1+b1)@w2+b2) ----------------
// Phase 0: each wave gathers 16 rows (d=128) into LDS sA (stride S1).
// Phase 1: GEMM1 (A from LDS, B from global) -> epilogue into LDS sT (stride S2, aliased).
// Phase 2: GEMM2 -> epilogue -> coalesced h1 store.
__global__ __launch_bounds__(256, 4) void layer1_fused(
    const short* __restrict__ x_bf,   // M x 128
    const int* __restrict__ rowptr, const int* __restrict__ srcs,
    const short* __restrict__ w1t,    // 256 x S1
    const float* __restrict__ b1,
    const short* __restrict__ w2t,    // 256 x S2
    const float* __restrict__ b2,
    short* __restrict__ h1,           // M x 256 (unpadded)
    int M)
{
    __shared__ short sBuf[64 * S2];   // 33792 B, aliased: sA (S1) then sT (S2)
    const int tid  = threadIdx.x;
    const int lane = tid & 63;
    const int wid  = tid >> 6;
    const int r16  = lane & 15;
    const int q    = lane >> 4;
    const int tm   = blockIdx.x * 64;
    const int wn   = wid * 64;

    // ---- phase 0: gather 16 rows per wave into sA ----
    {
        const int o = lane * 2;   // elem offset within 128
        for (int rr = 0; rr < 16; ++rr) {
            const int r = wid * 16 + rr;
            const int rg = tm + r;
            float a0 = 0.f, a1 = 0.f;
            if (rg < M) {
                const unsigned int u = *(const unsigned int*)(x_bf + (size_t)rg * 128 + o);
                a0 = bflo(u); a1 = bfhi(u);
                const int jb = rowptr[rg], je = rowptr[rg + 1];
                int j = jb;
                for (; j + 4 <= je; j += 4) {
                    const int s0 = srcs[j + 0];
                    const int s1 = srcs[j + 1];
                    const int s2 = srcs[j + 2];
                    const int s3 = srcs[j + 3];
                    const unsigned int v0 = *(const unsigned int*)(x_bf + (size_t)s0 * 128 + o);
                    const unsigned int v1 = *(const unsigned int*)(x_bf + (size_t)s1 * 128 + o);
                    const unsigned int v2 = *(const unsigned int*)(x_bf + (size_t)s2 * 128 + o);
                    const unsigned int v3 = *(const unsigned int*)(x_bf + (size_t)s3 * 128 + o);
                    a0 += bflo(v0); a1 += bfhi(v0);
                    a0 += bflo(v1); a1 += bfhi(v1);
                    a0 += bflo(v2); a1 += bfhi(v2);
                    a0 += bflo(v3); a1 += bfhi(v3);
                }
                for (; j < je; ++j) {
                    const unsigned int v = *(const unsigned int*)(x_bf + (size_t)srcs[j] * 128 + o);
                    a0 += bflo(v); a1 += bfhi(v);
                }
            }
            const unsigned int up = (unsigned int)f2bf(a0) | ((unsigned int)f2bf(a1) << 16);
            *(unsigned int*)(&sBuf[r * S1 + o]) = up;
        }
    }
    __syncthreads();

    f32x4 acc[4][4];
    #pragma unroll
    for (int i = 0; i < 4; ++i)
        #pragma unroll
        for (int j = 0; j < 4; ++j)
            acc[i][j] = (f32x4)0.f;

    // ---- GEMM1: K = 128, A from LDS (stride S1), B from global ----
    #pragma unroll
    for (int k0 = 0; k0 < 128; k0 += 32) {
        bf16x8 af[4], bfr[4];
        #pragma unroll
        for (int i = 0; i < 4; ++i)
            af[i] = *(const bf16x8*)(&sBuf[(i * 16 + r16) * S1 + k0 + q * 8]);
        #pragma unroll
        for (int j = 0; j < 4; ++j)
            bfr[j] = *(const bf16x8*)(w1t + (size_t)(wn + j * 16 + r16) * S1 + k0 + q * 8);
        #pragma unroll
        for (int i = 0; i < 4; ++i)
            #pragma unroll
            for (int j = 0; j < 4; ++j)
                acc[i][j] = __builtin_amdgcn_mfma_f32_16x16x32_bf16(af[i], bfr[j], acc[i][j], 0, 0, 0);
    }
    __syncthreads();   // done reading sA; sBuf may be overwritten as sT

    // epilogue1 -> sT (stride S2): row = i*16 + q*4 + r, col = wn + j*16 + r16
    #pragma unroll
    for (int j = 0; j < 4; ++j) {
        const int col = wn + j * 16 + r16;
        const float bj = b1[col];
        #pragma unroll
        for (int i = 0; i < 4; ++i)
            #pragma unroll
            for (int r = 0; r < 4; ++r) {
                float v = fmaxf(acc[i][j][r] + bj, 0.f);
                sBuf[(i * 16 + q * 4 + r) * S2 + col] = (short)f2bf(v);
            }
    }
    __syncthreads();

    // ---- GEMM2: K = 256, A from sT ----
    #pragma unroll
    for (int i = 0; i < 4; ++i)
        #pragma unroll
        for (int j = 0; j < 4; ++j)
            acc[i][j] = (f32x4)0.f;

    #pragma unroll
    for (int k0 = 0; k0 < 256; k0 += 32) {
        bf16x8 af[4], bfr[4];
        #pragma unroll
        for (int i = 0; i < 4; ++i)
            af[i] = *(const bf16x8*)(&sBuf[(i * 16 + r16) * S2 + k0 + q * 8]);
        #pragma unroll
        for (int j = 0; j < 4; ++j)
            bfr[j] = *(const bf16x8*)(w2t + (size_t)(wn + j * 16 + r16) * S2 + k0 + q * 8);
        #pragma unroll
        for (int i = 0; i < 4; ++i)
            #pragma unroll
            for (int j = 0; j < 4; ++j)
                acc[i][j] = __builtin_amdgcn_mfma_f32_16x16x32_bf16(af[i], bfr[j], acc[i][j], 0, 0, 0);
    }
    __syncthreads();

    // epilogue2 -> sT, then coalesced store
    #pragma unroll
    for (int j = 0; j < 4; ++j) {
        const int col = wn + j * 16 + r16;
        const float bj = b2[col];
        #pragma unroll
        for (int i = 0; i < 4; ++i)
            #pragma unroll
            for (int r = 0; r < 4; ++r) {
                float v = fmaxf(acc[i][j][r] + bj, 0.f);
                sBuf[(i * 16 + q * 4 + r) * S2 + col] = (short)f2bf(v);
            }
    }
    __syncthreads();

    #pragma unroll
    for (int c = 0; c < 8; ++c) {
        const int idx = tid + c * 256;
        const int row = idx >> 5;
        const int ch  = idx & 31;
        const int rg  = tm + row;
        if (rg < M) {
            const uint4 v = *(const uint4*)(&sBuf[row * S2 + ch * 8]);
            *(uint4*)(h1 + (size_t)rg * 256 + ch * 8) = v;
        }
    }
}

// ---------------- layer2: out = log_softmax(relu((h1+agg(h1))@w3+b3)@w4+b4) ----------------
__global__ __launch_bounds__(256, 4) void layer2_fused(
    const short* __restrict__ h1,     // M x 256
    const int* __restrict__ rowptr, const int* __restrict__ srcs,
    const short* __restrict__ w3t,    // 256 x S2
    const float* __restrict__ b3,
    const float* __restrict__ w4,     // 256 x 2 fp32
    const float* __restrict__ b4,
    float* __restrict__ out,          // M x 2
    int M)
{
    __shared__ short sBuf[64 * S2];   // aliased: sA (S2) then t2 tile (S2)
    const int tid  = threadIdx.x;
    const int lane = tid & 63;
    const int wid  = tid >> 6;
    const int r16  = lane & 15;
    const int q    = lane >> 4;
    const int tm   = blockIdx.x * 64;
    const int wn   = wid * 64;

    // ---- phase 0: gather 16 rows per wave (d=256) into sA ----
    {
        const int o = lane * 4;
        for (int rr = 0; rr < 16; ++rr) {
            const int r = wid * 16 + rr;
            const int rg = tm + r;
            float a0 = 0.f, a1 = 0.f, a2 = 0.f, a3 = 0.f;
            if (rg < M) {
                const uint2 u = *(const uint2*)(h1 + (size_t)rg * 256 + o);
                a0 = bflo(u.x); a1 = bfhi(u.x); a2 = bflo(u.y); a3 = bfhi(u.y);
                const int jb = rowptr[rg], je = rowptr[rg + 1];
                int j = jb;
                for (; j + 4 <= je; j += 4) {
                    const int s0 = srcs[j + 0];
                    const int s1 = srcs[j + 1];
                    const int s2 = srcs[j + 2];
                    const int s3 = srcs[j + 3];
                    const uint2 v0 = *(const uint2*)(h1 + (size_t)s0 * 256 + o);
                    const uint2 v1 = *(const uint2*)(h1 + (size_t)s1 * 256 + o);
                    const uint2 v2 = *(const uint2*)(h1 + (size_t)s2 * 256 + o);
                    const uint2 v3 = *(const uint2*)(h1 + (size_t)s3 * 256 + o);
                    a0 += bflo(v0.x); a1 += bfhi(v0.x); a2 += bflo(v0.y); a3 += bfhi(v0.y);
                    a0 += bflo(v1.x); a1 += bfhi(v1.x); a2 += bflo(v1.y); a3 += bfhi(v1.y);
                    a0 += bflo(v2.x); a1 += bfhi(v2.x); a2 += bflo(v2.y); a3 += bfhi(v2.y);
                    a0 += bflo(v3.x); a1 += bfhi(v3.x); a2 += bflo(v3.y); a3 += bfhi(v3.y);
                }
                for (; j < je; ++j) {
                    const uint2 v = *(const uint2*)(h1 + (size_t)srcs[j] * 256 + o);
                    a0 += bflo(v.x); a1 += bfhi(v.x); a2 += bflo(v.y); a3 += bfhi(v.y);
                }
            }
            uint2 up;
            up.x = (unsigned int)f2bf(a0) | ((unsigned int)f2bf(a1) << 16);
            up.y = (unsigned int)f2bf(a2) | ((unsigned int)f2bf(a3) << 16);
            *(uint2*)(&sBuf[r * S2 + o]) = up;
        }
    }
    __syncthreads();

    f32x4 acc[4][4];
    #pragma unroll
    for (int i = 0; i < 4; ++i)
        #pragma unroll
        for (int j = 0; j < 4; ++j)
            acc[i][j] = (f32x4)0.f;

    // ---- GEMM3: K = 256, A from LDS sA ----
    #pragma unroll
    for (int k0 = 0; k0 < 256; k0 += 32) {
        bf16x8 af[4], bfr[4];
        #pragma unroll
        for (int i = 0; i < 4; ++i)
            af[i] = *(const bf16x8*)(&sBuf[(i * 16 + r16) * S2 + k0 + q * 8]);
        #pragma unroll
        for (int j = 0; j < 4; ++j)
            bfr[j] = *(const bf16x8*)(w3t + (size_t)(wn + j * 16 + r16) * S2 + k0 + q * 8);
        #pragma unroll
        for (int i = 0; i < 4; ++i)
            #pragma unroll
            for (int j = 0; j < 4; ++j)
                acc[i][j] = __builtin_amdgcn_mfma_f32_16x16x32_bf16(af[i], bfr[j], acc[i][j], 0, 0, 0);
    }
    __syncthreads();   // done reading sA; reuse as t2 tile

    // epilogue -> t2 tile (bf16, relu+bias)
    #pragma unroll
    for (int j = 0; j < 4; ++j) {
        const int col = wn + j * 16 + r16;
        const float bj = b3[col];
        #pragma unroll
        for (int i = 0; i < 4; ++i)
            #pragma unroll
            for (int r = 0; r < 4; ++r) {
                float v = fmaxf(acc[i][j][r] + bj, 0.f);
                sBuf[(i * 16 + q * 4 + r) * S2 + col] = (short)f2bf(v);
            }
    }
    __syncthreads();

    // head: 4 threads per row, 64 k each; shuffle-reduce width 4
    const int row = tid >> 2;
    const int qd  = tid & 3;
    const short* tp = &sBuf[row * S2 + qd * 64];
    const float* w4p = w4 + qd * 128;
    float s0 = 0.f, s1 = 0.f;
    #pragma unroll 8
    for (int k = 0; k < 64; ++k) {
        const float a = bf2f((unsigned short)tp[k]);
        const float2 w = *(const float2*)(w4p + 2 * k);
        s0 = fmaf(a, w.x, s0);
        s1 = fmaf(a, w.y, s1);
    }
    s0 += __shfl_down(s0, 2, 4);  s1 += __shfl_down(s1, 2, 4);
    s0 += __shfl_down(s0, 1, 4);  s1 += __shfl_down(s1, 1, 4);
    if (qd == 0) {
        const int rg = tm + row;
        if (rg < M) {
            s0 += b4[0];
            s1 += b4[1];
            const float m = fmaxf(s0, s1);
            const float l = logf(__expf(s0 - m) + __expf(s1 - m));
            float2 o;
            o.x = s0 - m - l;
            o.y = s1 - m - l;
            *(float2*)(out + (size_t)rg * 2) = o;
        }
    }
}

extern "C" void kernel_launch(void* const* d_in, const int* in_sizes, int n_in,
                              void* d_out, int out_size, void* d_ws, size_t ws_size,
                              hipStream_t stream)
{
    const float* x  = (const float*)d_in[0];
    const int*   ei = (const int*)d_in[1];
    const float* w1 = (const float*)d_in[2];
    const float* b1 = (const float*)d_in[3];
    const float* w2 = (const float*)d_in[4];
    const float* b2 = (const float*)d_in[5];
    const float* w3 = (const float*)d_in[6];
    const float* b3 = (const float*)d_in[7];
    const float* w4 = (const float*)d_in[8];
    const float* b4 = (const float*)d_in[9];

    const int DIN = 128, DH = 256;
    const int M = in_sizes[0] / DIN;   // 50000
    const int E = in_sizes[1] / 2;     // 600000
    const int* src = ei;
    const int* dst = ei + E;
    const int nB = (M + 1023) / 1024;  // <= 64

    // -------- workspace layout --------
    int* deg    = (int*)d_ws;
    int* cur    = deg + M;
    int* rowptr = cur + M;
    int* bsum   = rowptr + (M + 1);
    int* boff   = bsum + 64;
    int* srcs   = boff + 64;
    size_t off = ((size_t)(3 * M + 1 + 128 + E) * sizeof(int) + 255) & ~(size_t)255;
    short* x_bf = (short*)((char*)d_ws + off);  off += (size_t)M * DIN * 2;   // M x 128
    off = (off + 255) & ~(size_t)255;
    short* h1   = (short*)((char*)d_ws + off);  off += (size_t)M * DH * 2;    // M x 256
    off = (off + 255) & ~(size_t)255;
    short* w1t  = (short*)((char*)d_ws + off);  off += (size_t)DH * S1 * 2;   // 256 x 136
    off = (off + 255) & ~(size_t)255;
    short* w2t  = (short*)((char*)d_ws + off);  off += (size_t)DH * S2 * 2;   // 256 x 264
    off = (off + 255) & ~(size_t)255;
    short* w3t  = (short*)((char*)d_ws + off);  off += (size_t)DH * S2 * 2;   // 256 x 264

    // -------- CSR build --------
    hipMemsetAsync(deg, 0, (size_t)M * sizeof(int), stream);
    degree_kernel<<<(E + 255) / 256, 256, 0, stream>>>(dst, deg, E);
    block_sum_kernel<<<nB, 256, 0, stream>>>(deg, bsum, M);
    scan_partials_kernel<<<1, 64, 0, stream>>>(bsum, boff, nB);
    scan_blocks_kernel<<<nB, 256, 0, stream>>>(deg, boff, rowptr, cur, M, E);
    fill_kernel<<<(E + 255) / 256, 256, 0, stream>>>(src, dst, cur, srcs, E);

    // -------- converts --------
    cvt_bf16_kernel<<<((M * DIN / 4) + 255) / 256, 256, 0, stream>>>(x, x_bf, M * DIN / 4);
    transpose_cvt3_kernel<<<dim3(8, 8, 3), 256, 0, stream>>>(w1, w2, w3, w1t, w2t, w3t);

    const int nblk = (M + 63) / 64;

    // -------- fused layers --------
    layer1_fused<<<nblk, 256, 0, stream>>>(x_bf, rowptr, srcs, w1t, b1, w2t, b2, h1, M);
    layer2_fused<<<nblk, 256, 0, stream>>>(h1, rowptr, srcs, w3t, b3, w4, b4, (float*)d_out, M);
}

// Round 7
// 289.015 us; speedup vs baseline: 1.1003x; 1.1003x over previous
//
#include <hip/hip_runtime.h>
#include <hip/hip_bf16.h>

// GIN 2-layer forward — R7: R5 structure (unfused gathers — R6 fusion
// regressed: occupancy 62->28 killed the latency-bound gather), with
// gather MLP deepened to unroll-8.
//
//   CSR build: degree -> block_sum -> scan_partials -> scan_blocks -> fill
//   x_bf  = bf16(x);  w{1,2,3}t = bf16(w^T) padded (merged launch)
//   h1in  = x_bf + gather(x_bf)                     [bf16, stride 136]
//   h1    = relu(relu(h1in@w1+b1)@w2+b2)            [layer1_fused, t1 in LDS only]
//   h2in  = h1 + gather(h1)                         [bf16, stride 264]
//   out   = log_softmax(relu(h2in@w3+b3)@w4+b4)     [layer2_fused, t2 in LDS only]

typedef __attribute__((ext_vector_type(8))) short bf16x8;
typedef __attribute__((ext_vector_type(4))) float f32x4;

static __device__ __forceinline__ unsigned short f2bf(float f) {
    unsigned int u = __float_as_uint(f);
    unsigned int r = (u + 0x7fffu + ((u >> 16) & 1u)) >> 16;
    return (unsigned short)r;
}
static __device__ __forceinline__ float bf2f(unsigned short s) {
    return __uint_as_float(((unsigned int)s) << 16);
}
static __device__ __forceinline__ float bflo(unsigned int u) {
    return __uint_as_float(u << 16);
}
static __device__ __forceinline__ float bfhi(unsigned int u) {
    return __uint_as_float(u & 0xffff0000u);
}

#define S1 136   // 128 + 8 pad (bf16 elems)
#define S2 264   // 256 + 8 pad

// ---------------- CSR build ----------------
__global__ __launch_bounds__(256) void degree_kernel(
    const int* __restrict__ dst, int* __restrict__ deg, int E)
{
    const int e = blockIdx.x * 256 + threadIdx.x;
    if (e < E) atomicAdd(&deg[dst[e]], 1);
}

__global__ __launch_bounds__(256) void block_sum_kernel(
    const int* __restrict__ deg, int* __restrict__ bsum, int M)
{
    const int b = blockIdx.x, t = threadIdx.x;
    const int idx = b * 1024 + t * 4;
    int s = 0;
    if (idx + 3 < M) {
        const int4 v = *(const int4*)(deg + idx);
        s = v.x + v.y + v.z + v.w;
    } else {
        #pragma unroll
        for (int i = 0; i < 4; ++i) if (idx + i < M) s += deg[idx + i];
    }
    #pragma unroll
    for (int off = 32; off > 0; off >>= 1) s += __shfl_down(s, off);
    __shared__ int ws[4];
    if ((t & 63) == 0) ws[t >> 6] = s;
    __syncthreads();
    if (t == 0) bsum[b] = ws[0] + ws[1] + ws[2] + ws[3];
}

__global__ __launch_bounds__(64) void scan_partials_kernel(
    const int* __restrict__ bsum, int* __restrict__ boff, int nB)
{
    const int t = threadIdx.x;
    const int v = (t < nB) ? bsum[t] : 0;
    int inc = v;
    #pragma unroll
    for (int off = 1; off < 64; off <<= 1) {
        const int u = __shfl_up(inc, off);
        if (t >= off) inc += u;
    }
    if (t < nB) boff[t] = inc - v;
}

__global__ __launch_bounds__(256) void scan_blocks_kernel(
    const int* __restrict__ deg, const int* __restrict__ boff,
    int* __restrict__ rowptr, int* __restrict__ cur, int M, int E)
{
    const int b = blockIdx.x, t = threadIdx.x;
    const int idx = b * 1024 + t * 4;
    int4 d = make_int4(0, 0, 0, 0);
    if (idx + 3 < M) {
        d = *(const int4*)(deg + idx);
    } else {
        if (idx + 0 < M) d.x = deg[idx + 0];
        if (idx + 1 < M) d.y = deg[idx + 1];
        if (idx + 2 < M) d.z = deg[idx + 2];
        if (idx + 3 < M) d.w = deg[idx + 3];
    }
    const int tot = d.x + d.y + d.z + d.w;
    const int lane = t & 63, wid = t >> 6;
    int inc = tot;
    #pragma unroll
    for (int off = 1; off < 64; off <<= 1) {
        const int u = __shfl_up(inc, off);
        if (lane >= off) inc += u;
    }
    __shared__ int wsum[4];
    if (lane == 63) wsum[wid] = inc;
    __syncthreads();
    int woff = 0;
    #pragma unroll
    for (int w = 0; w < 4; ++w) if (w < wid) woff += wsum[w];
    int p = boff[b] + woff + (inc - tot);
    if (idx + 0 < M) { rowptr[idx + 0] = p; cur[idx + 0] = p; } p += d.x;
    if (idx + 1 < M) { rowptr[idx + 1] = p; cur[idx + 1] = p; } p += d.y;
    if (idx + 2 < M) { rowptr[idx + 2] = p; cur[idx + 2] = p; } p += d.z;
    if (idx + 3 < M) { rowptr[idx + 3] = p; cur[idx + 3] = p; }
    if (b == 0 && t == 0) rowptr[M] = E;
}

__global__ __launch_bounds__(256) void fill_kernel(
    const int* __restrict__ src, const int* __restrict__ dst,
    int* __restrict__ cur, int* __restrict__ srcs, int E)
{
    const int e = blockIdx.x * 256 + threadIdx.x;
    if (e >= E) return;
    const int p = atomicAdd(&cur[dst[e]], 1);
    srcs[p] = src[e];
}

// ---------------- converts ----------------
__global__ __launch_bounds__(256) void cvt_bf16_kernel(
    const float* __restrict__ in, short* __restrict__ outb, int n4)
{
    const int i = (blockIdx.x * 256 + threadIdx.x);
    if (i >= n4) return;
    const float4 v = *(const float4*)(in + (size_t)i * 4);
    ushort4 o;
    o.x = f2bf(v.x); o.y = f2bf(v.y); o.z = f2bf(v.z); o.w = f2bf(v.w);
    *(ushort4*)(outb + (size_t)i * 4) = o;
}

// merged 3-way transpose: out[n][k] (bf16, padded) = in[k][n] (fp32)
__global__ __launch_bounds__(256) void transpose_cvt3_kernel(
    const float* __restrict__ w1, const float* __restrict__ w2, const float* __restrict__ w3,
    short* __restrict__ w1t, short* __restrict__ w2t, short* __restrict__ w3t)
{
    const int z = blockIdx.z;
    const float* in; short* outb; int K, ostride;
    if (z == 0)      { in = w1; outb = w1t; K = 128; ostride = S1; }
    else if (z == 1) { in = w2; outb = w2t; K = 256; ostride = S2; }
    else             { in = w3; outb = w3t; K = 256; ostride = S2; }
    const int N = 256;
    const int k0 = blockIdx.x * 32;
    if (k0 >= K) return;
    const int n0 = blockIdx.y * 32;
    __shared__ float tile[32][33];
    const int tx = threadIdx.x & 31;
    const int ty = threadIdx.x >> 5;   // 0..7
    #pragma unroll
    for (int i = 0; i < 4; ++i)
        tile[ty + 8 * i][tx] = in[(size_t)(k0 + ty + 8 * i) * N + n0 + tx];
    __syncthreads();
    #pragma unroll
    for (int i = 0; i < 4; ++i)
        outb[(size_t)(n0 + ty + 8 * i) * ostride + k0 + tx] = (short)f2bf(tile[tx][ty + 8 * i]);
}

// ---------------- gathers (bf16 in/out, fp32 accumulate, 8x unrolled) ----------------
__global__ __launch_bounds__(256) void gather_add_d128(
    const short* __restrict__ feat,    // M x 128 (unpadded)
    const int* __restrict__ rowptr, const int* __restrict__ srcs,
    short* __restrict__ outb, int M)   // M x S1
{
    const int row = blockIdx.x * 4 + (threadIdx.x >> 6);
    if (row >= M) return;
    const int o = (threadIdx.x & 63) * 2;
    const unsigned int u = *(const unsigned int*)(feat + (size_t)row * 128 + o);
    float a0 = bflo(u), a1 = bfhi(u);
    const int jb = rowptr[row], je = rowptr[row + 1];
    int j = jb;
    for (; j + 8 <= je; j += 8) {
        unsigned int v[8];
        #pragma unroll
        for (int t = 0; t < 8; ++t) {
            const int s = srcs[j + t];
            v[t] = *(const unsigned int*)(feat + (size_t)s * 128 + o);
        }
        #pragma unroll
        for (int t = 0; t < 8; ++t) { a0 += bflo(v[t]); a1 += bfhi(v[t]); }
    }
    if (j + 4 <= je) {
        unsigned int v[4];
        #pragma unroll
        for (int t = 0; t < 4; ++t) {
            const int s = srcs[j + t];
            v[t] = *(const unsigned int*)(feat + (size_t)s * 128 + o);
        }
        #pragma unroll
        for (int t = 0; t < 4; ++t) { a0 += bflo(v[t]); a1 += bfhi(v[t]); }
        j += 4;
    }
    for (; j < je; ++j) {
        const unsigned int v = *(const unsigned int*)(feat + (size_t)srcs[j] * 128 + o);
        a0 += bflo(v); a1 += bfhi(v);
    }
    const unsigned int up = (unsigned int)f2bf(a0) | ((unsigned int)f2bf(a1) << 16);
    *(unsigned int*)(outb + (size_t)row * S1 + o) = up;
}

__global__ __launch_bounds__(256) void gather_add_d256(
    const short* __restrict__ feat,    // M x 256 (unpadded)
    const int* __restrict__ rowptr, const int* __restrict__ srcs,
    short* __restrict__ outb, int M)   // M x S2
{
    const int row = blockIdx.x * 4 + (threadIdx.x >> 6);
    if (row >= M) return;
    const int o = (threadIdx.x & 63) * 4;
    const uint2 u = *(const uint2*)(feat + (size_t)row * 256 + o);
    float a0 = bflo(u.x), a1 = bfhi(u.x);
    float a2 = bflo(u.y), a3 = bfhi(u.y);
    const int jb = rowptr[row], je = rowptr[row + 1];
    int j = jb;
    for (; j + 8 <= je; j += 8) {
        uint2 v[8];
        #pragma unroll
        for (int t = 0; t < 8; ++t) {
            const int s = srcs[j + t];
            v[t] = *(const uint2*)(feat + (size_t)s * 256 + o);
        }
        #pragma unroll
        for (int t = 0; t < 8; ++t) {
            a0 += bflo(v[t].x); a1 += bfhi(v[t].x);
            a2 += bflo(v[t].y); a3 += bfhi(v[t].y);
        }
    }
    if (j + 4 <= je) {
        uint2 v[4];
        #pragma unroll
        for (int t = 0; t < 4; ++t) {
            const int s = srcs[j + t];
            v[t] = *(const uint2*)(feat + (size_t)s * 256 + o);
        }
        #pragma unroll
        for (int t = 0; t < 4; ++t) {
            a0 += bflo(v[t].x); a1 += bfhi(v[t].x);
            a2 += bflo(v[t].y); a3 += bfhi(v[t].y);
        }
        j += 4;
    }
    for (; j < je; ++j) {
        const uint2 v = *(const uint2*)(feat + (size_t)srcs[j] * 256 + o);
        a0 += bflo(v.x); a1 += bfhi(v.x); a2 += bflo(v.y); a3 += bfhi(v.y);
    }
    uint2 up;
    up.x = (unsigned int)f2bf(a0) | ((unsigned int)f2bf(a1) << 16);
    up.y = (unsigned int)f2bf(a2) | ((unsigned int)f2bf(a3) << 16);
    *(uint2*)(outb + (size_t)row * S2 + o) = up;
}

// ---------------- layer1: h1 = relu(relu(h1in@w1+b1)@w2+b2) ----------------
__global__ __launch_bounds__(256) void layer1_fused(
    const short* __restrict__ h1in,   // M x S1 (payload 128)
    const short* __restrict__ w1t,    // 256 x S1 (payload 128)
    const float* __restrict__ b1,
    const short* __restrict__ w2t,    // 256 x S2 (payload 256)
    const float* __restrict__ b2,
    short* __restrict__ h1,           // M x 256 (unpadded)
    int M)
{
    __shared__ short sT[64 * S2];
    const int tid  = threadIdx.x;
    const int lane = tid & 63;
    const int wid  = tid >> 6;
    const int r16  = lane & 15;
    const int q    = lane >> 4;
    const int tm   = blockIdx.x * 64;
    const int wn   = wid * 64;

    f32x4 acc[4][4];
    #pragma unroll
    for (int i = 0; i < 4; ++i)
        #pragma unroll
        for (int j = 0; j < 4; ++j)
            acc[i][j] = (f32x4)0.f;

    // ---- GEMM1: t1 = relu(h1in @ w1 + b1), K = 128 ----
    const short* Abase = h1in + (size_t)tm * S1;
    #pragma unroll
    for (int k0 = 0; k0 < 128; k0 += 32) {
        bf16x8 af[4], bfr[4];
        #pragma unroll
        for (int i = 0; i < 4; ++i)
            af[i] = *(const bf16x8*)(Abase + (size_t)(i * 16 + r16) * S1 + k0 + q * 8);
        #pragma unroll
        for (int j = 0; j < 4; ++j)
            bfr[j] = *(const bf16x8*)(w1t + (size_t)(wn + j * 16 + r16) * S1 + k0 + q * 8);
        #pragma unroll
        for (int i = 0; i < 4; ++i)
            #pragma unroll
            for (int j = 0; j < 4; ++j)
                acc[i][j] = __builtin_amdgcn_mfma_f32_16x16x32_bf16(af[i], bfr[j], acc[i][j], 0, 0, 0);
    }

    // epilogue1 -> sT  (row = i*16 + q*4 + r, col = wn + j*16 + r16)
    #pragma unroll
    for (int j = 0; j < 4; ++j) {
        const int col = wn + j * 16 + r16;
        const float bj = b1[col];
        #pragma unroll
        for (int i = 0; i < 4; ++i)
            #pragma unroll
            for (int r = 0; r < 4; ++r) {
                float v = fmaxf(acc[i][j][r] + bj, 0.f);
                sT[(i * 16 + q * 4 + r) * S2 + col] = (short)f2bf(v);
            }
    }
    __syncthreads();

    // ---- GEMM2: h1 = relu(t1 @ w2 + b2), K = 256, A from LDS ----
    #pragma unroll
    for (int i = 0; i < 4; ++i)
        #pragma unroll
        for (int j = 0; j < 4; ++j)
            acc[i][j] = (f32x4)0.f;

    #pragma unroll
    for (int k0 = 0; k0 < 256; k0 += 32) {
        bf16x8 af[4], bfr[4];
        #pragma unroll
        for (int i = 0; i < 4; ++i)
            af[i] = *(const bf16x8*)(&sT[(i * 16 + r16) * S2 + k0 + q * 8]);
        #pragma unroll
        for (int j = 0; j < 4; ++j)
            bfr[j] = *(const bf16x8*)(w2t + (size_t)(wn + j * 16 + r16) * S2 + k0 + q * 8);
        #pragma unroll
        for (int i = 0; i < 4; ++i)
            #pragma unroll
            for (int j = 0; j < 4; ++j)
                acc[i][j] = __builtin_amdgcn_mfma_f32_16x16x32_bf16(af[i], bfr[j], acc[i][j], 0, 0, 0);
    }
    __syncthreads();   // all waves done reading sT

    // epilogue2 -> sT (reused as h1 tile), then coalesced store
    #pragma unroll
    for (int j = 0; j < 4; ++j) {
        const int col = wn + j * 16 + r16;
        const float bj = b2[col];
        #pragma unroll
        for (int i = 0; i < 4; ++i)
            #pragma unroll
            for (int r = 0; r < 4; ++r) {
                float v = fmaxf(acc[i][j][r] + bj, 0.f);
                sT[(i * 16 + q * 4 + r) * S2 + col] = (short)f2bf(v);
            }
    }
    __syncthreads();

    #pragma unroll
    for (int c = 0; c < 8; ++c) {
        const int idx = tid + c * 256;
        const int row = idx >> 5;
        const int ch  = idx & 31;
        const int rg  = tm + row;
        if (rg < M) {
            const uint4 v = *(const uint4*)(&sT[row * S2 + ch * 8]);
            *(uint4*)(h1 + (size_t)rg * 256 + ch * 8) = v;
        }
    }
}

// ---------------- layer2: out = log_softmax(relu(h2in@w3+b3) @ w4 + b4) ----------------
__global__ __launch_bounds__(256) void layer2_fused(
    const short* __restrict__ h2in,   // M x S2 (payload 256)
    const short* __restrict__ w3t,    // 256 x S2
    const float* __restrict__ b3,
    const float* __restrict__ w4,     // 256 x 2 fp32
    const float* __restrict__ b4,
    float* __restrict__ out,          // M x 2
    int M)
{
    __shared__ short sT[64 * S2];
    const int tid  = threadIdx.x;
    const int lane = tid & 63;
    const int wid  = tid >> 6;
    const int r16  = lane & 15;
    const int q    = lane >> 4;
    const int tm   = blockIdx.x * 64;
    const int wn   = wid * 64;

    f32x4 acc[4][4];
    #pragma unroll
    for (int i = 0; i < 4; ++i)
        #pragma unroll
        for (int j = 0; j < 4; ++j)
            acc[i][j] = (f32x4)0.f;

    const short* Abase = h2in + (size_t)tm * S2;
    #pragma unroll
    for (int k0 = 0; k0 < 256; k0 += 32) {
        bf16x8 af[4], bfr[4];
        #pragma unroll
        for (int i = 0; i < 4; ++i)
            af[i] = *(const bf16x8*)(Abase + (size_t)(i * 16 + r16) * S2 + k0 + q * 8);
        #pragma unroll
        for (int j = 0; j < 4; ++j)
            bfr[j] = *(const bf16x8*)(w3t + (size_t)(wn + j * 16 + r16) * S2 + k0 + q * 8);
        #pragma unroll
        for (int i = 0; i < 4; ++i)
            #pragma unroll
            for (int j = 0; j < 4; ++j)
                acc[i][j] = __builtin_amdgcn_mfma_f32_16x16x32_bf16(af[i], bfr[j], acc[i][j], 0, 0, 0);
    }

    // epilogue -> sT (t2 tile, bf16 + relu + bias)
    #pragma unroll
    for (int j = 0; j < 4; ++j) {
        const int col = wn + j * 16 + r16;
        const float bj = b3[col];
        #pragma unroll
        for (int i = 0; i < 4; ++i)
            #pragma unroll
            for (int r = 0; r < 4; ++r) {
                float v = fmaxf(acc[i][j][r] + bj, 0.f);
                sT[(i * 16 + q * 4 + r) * S2 + col] = (short)f2bf(v);
            }
    }
    __syncthreads();

    // head: 4 threads per row, 64 k each; shuffle-reduce width 4
    const int row = tid >> 2;
    const int qd  = tid & 3;
    const short* tp = &sT[row * S2 + qd * 64];
    const float* w4p = w4 + qd * 128;
    float s0 = 0.f, s1 = 0.f;
    #pragma unroll 8
    for (int k = 0; k < 64; ++k) {
        const float a = bf2f((unsigned short)tp[k]);
        const float2 w = *(const float2*)(w4p + 2 * k);
        s0 = fmaf(a, w.x, s0);
        s1 = fmaf(a, w.y, s1);
    }
    s0 += __shfl_down(s0, 2, 4);  s1 += __shfl_down(s1, 2, 4);
    s0 += __shfl_down(s0, 1, 4);  s1 += __shfl_down(s1, 1, 4);
    if (qd == 0) {
        const int rg = tm + row;
        if (rg < M) {
            s0 += b4[0];
            s1 += b4[1];
            const float m = fmaxf(s0, s1);
            const float l = logf(__expf(s0 - m) + __expf(s1 - m));
            float2 o;
            o.x = s0 - m - l;
            o.y = s1 - m - l;
            *(float2*)(out + (size_t)rg * 2) = o;
        }
    }
}

extern "C" void kernel_launch(void* const* d_in, const int* in_sizes, int n_in,
                              void* d_out, int out_size, void* d_ws, size_t ws_size,
                              hipStream_t stream)
{
    const float* x  = (const float*)d_in[0];
    const int*   ei = (const int*)d_in[1];
    const float* w1 = (const float*)d_in[2];
    const float* b1 = (const float*)d_in[3];
    const float* w2 = (const float*)d_in[4];
    const float* b2 = (const float*)d_in[5];
    const float* w3 = (const float*)d_in[6];
    const float* b3 = (const float*)d_in[7];
    const float* w4 = (const float*)d_in[8];
    const float* b4 = (const float*)d_in[9];

    const int DIN = 128, DH = 256;
    const int M = in_sizes[0] / DIN;   // 50000
    const int E = in_sizes[1] / 2;     // 600000
    const int* src = ei;
    const int* dst = ei + E;
    const int nB = (M + 1023) / 1024;  // <= 64

    // -------- workspace layout --------
    int* deg    = (int*)d_ws;
    int* cur    = deg + M;
    int* rowptr = cur + M;
    int* bsum   = rowptr + (M + 1);
    int* boff   = bsum + 64;
    int* srcs   = boff + 64;
    size_t off = ((size_t)(3 * M + 1 + 128 + E) * sizeof(int) + 255) & ~(size_t)255;
    short* x_bf = (short*)((char*)d_ws + off);  off += (size_t)M * DIN * 2;   // M x 128
    off = (off + 255) & ~(size_t)255;
    short* h1in = (short*)((char*)d_ws + off);  off += (size_t)M * S1 * 2;    // M x 136
    off = (off + 255) & ~(size_t)255;
    short* h1   = (short*)((char*)d_ws + off);  off += (size_t)M * DH * 2;    // M x 256
    off = (off + 255) & ~(size_t)255;
    short* h2in = (short*)((char*)d_ws + off);  off += (size_t)M * S2 * 2;    // M x 264
    off = (off + 255) & ~(size_t)255;
    short* w1t  = (short*)((char*)d_ws + off);  off += (size_t)DH * S1 * 2;   // 256 x 136
    off = (off + 255) & ~(size_t)255;
    short* w2t  = (short*)((char*)d_ws + off);  off += (size_t)DH * S2 * 2;   // 256 x 264
    off = (off + 255) & ~(size_t)255;
    short* w3t  = (short*)((char*)d_ws + off);  off += (size_t)DH * S2 * 2;   // 256 x 264

    // -------- CSR build --------
    hipMemsetAsync(deg, 0, (size_t)M * sizeof(int), stream);
    degree_kernel<<<(E + 255) / 256, 256, 0, stream>>>(dst, deg, E);
    block_sum_kernel<<<nB, 256, 0, stream>>>(deg, bsum, M);
    scan_partials_kernel<<<1, 64, 0, stream>>>(bsum, boff, nB);
    scan_blocks_kernel<<<nB, 256, 0, stream>>>(deg, boff, rowptr, cur, M, E);
    fill_kernel<<<(E + 255) / 256, 256, 0, stream>>>(src, dst, cur, srcs, E);

    // -------- converts --------
    cvt_bf16_kernel<<<((M * DIN / 4) + 255) / 256, 256, 0, stream>>>(x, x_bf, M * DIN / 4);
    transpose_cvt3_kernel<<<dim3(8, 8, 3), 256, 0, stream>>>(w1, w2, w3, w1t, w2t, w3t);

    const int nblk = (M + 63) / 64;

    // -------- layer 1 --------
    gather_add_d128<<<(M + 3) / 4, 256, 0, stream>>>(x_bf, rowptr, srcs, h1in, M);
    layer1_fused<<<nblk, 256, 0, stream>>>(h1in, w1t, b1, w2t, b2, h1, M);

    // -------- layer 2 --------
    gather_add_d256<<<(M + 3) / 4, 256, 0, stream>>>(h1, rowptr, srcs, h2in, M);
    layer2_fused<<<nblk, 256, 0, stream>>>(h2in, w3t, b3, w4, b4, (float*)d_out, M);
}

// Round 8
// 285.068 us; speedup vs baseline: 1.1156x; 1.0138x over previous
//
#include <hip/hip_runtime.h>
#include <hip/hip_bf16.h>

// GIN 2-layer forward — R8: R7 + (a) dispatch merge 14->9 (prep kernel zeroes
// deg + converts x + transposes weights; scan_partials folded into scan_blocks),
// (b) gathers restructured to 2-neighbors-per-wave with 16B/8B per lane.
//
//   prep: zero deg | x_bf = bf16(x) | w{1,2,3}t = bf16(w^T) padded
//   CSR: degree -> block_sum -> scan_blocks2 -> fill
//   h1in  = x_bf + gather(x_bf)                     [bf16, stride 136]
//   h1    = relu(relu(h1in@w1+b1)@w2+b2)            [layer1_fused, t1 in LDS only]
//   h2in  = h1 + gather(h1)                         [bf16, stride 264]
//   out   = log_softmax(relu(h2in@w3+b3)@w4+b4)     [layer2_fused, t2 in LDS only]

typedef __attribute__((ext_vector_type(8))) short bf16x8;
typedef __attribute__((ext_vector_type(4))) float f32x4;

static __device__ __forceinline__ unsigned short f2bf(float f) {
    unsigned int u = __float_as_uint(f);
    unsigned int r = (u + 0x7fffu + ((u >> 16) & 1u)) >> 16;
    return (unsigned short)r;
}
static __device__ __forceinline__ float bf2f(unsigned short s) {
    return __uint_as_float(((unsigned int)s) << 16);
}
static __device__ __forceinline__ float bflo(unsigned int u) {
    return __uint_as_float(u << 16);
}
static __device__ __forceinline__ float bfhi(unsigned int u) {
    return __uint_as_float(u & 0xffff0000u);
}

#define S1 136   // 128 + 8 pad (bf16 elems)
#define S2 264   // 256 + 8 pad

// ---------------- prep: zero deg | cvt x | transpose w1/w2/w3 ----------------
__global__ __launch_bounds__(256) void prep_kernel(
    const float* __restrict__ x, short* __restrict__ x_bf,
    const float* __restrict__ w1, const float* __restrict__ w2, const float* __restrict__ w3,
    short* __restrict__ w1t, short* __restrict__ w2t, short* __restrict__ w3t,
    int* __restrict__ deg, int M, int zB, int cB)
{
    const int b = blockIdx.x;
    const int t = threadIdx.x;
    if (b < zB) {
        // zero deg[M]
        const int idx = b * 1024 + t * 4;
        if (idx + 3 < M) {
            *(int4*)(deg + idx) = make_int4(0, 0, 0, 0);
        } else {
            #pragma unroll
            for (int i = 0; i < 4; ++i) if (idx + i < M) deg[idx + i] = 0;
        }
        return;
    }
    if (b < zB + cB) {
        // cvt x -> bf16, 4 elems/thread
        const int i = (b - zB) * 256 + t;
        const int n4 = M * 32;   // M*128/4
        if (i >= n4) return;
        const float4 v = *(const float4*)(x + (size_t)i * 4);
        ushort4 o;
        o.x = f2bf(v.x); o.y = f2bf(v.y); o.z = f2bf(v.z); o.w = f2bf(v.w);
        *(ushort4*)(x_bf + (size_t)i * 4) = o;
        return;
    }
    // transpose-convert: 192 blocks: z in [0,3), 8x8 (k,n) tiles of 32
    const int tb = b - zB - cB;
    const int z = tb >> 6;
    const int rem = tb & 63;
    const int kb = rem & 7;
    const int nb = rem >> 3;
    const float* in; short* outb; int K, ostride;
    if (z == 0)      { in = w1; outb = w1t; K = 128; ostride = S1; }
    else if (z == 1) { in = w2; outb = w2t; K = 256; ostride = S2; }
    else             { in = w3; outb = w3t; K = 256; ostride = S2; }
    const int N = 256;
    const int k0 = kb * 32;
    if (k0 >= K) return;
    const int n0 = nb * 32;
    __shared__ float tile[32][33];
    const int tx = t & 31;
    const int ty = t >> 5;   // 0..7
    #pragma unroll
    for (int i = 0; i < 4; ++i)
        tile[ty + 8 * i][tx] = in[(size_t)(k0 + ty + 8 * i) * N + n0 + tx];
    __syncthreads();
    #pragma unroll
    for (int i = 0; i < 4; ++i)
        outb[(size_t)(n0 + ty + 8 * i) * ostride + k0 + tx] = (short)f2bf(tile[tx][ty + 8 * i]);
}

// ---------------- CSR build ----------------
__global__ __launch_bounds__(256) void degree_kernel(
    const int* __restrict__ dst, int* __restrict__ deg, int E)
{
    const int e = blockIdx.x * 256 + threadIdx.x;
    if (e < E) atomicAdd(&deg[dst[e]], 1);
}

__global__ __launch_bounds__(256) void block_sum_kernel(
    const int* __restrict__ deg, int* __restrict__ bsum, int M)
{
    const int b = blockIdx.x, t = threadIdx.x;
    const int idx = b * 1024 + t * 4;
    int s = 0;
    if (idx + 3 < M) {
        const int4 v = *(const int4*)(deg + idx);
        s = v.x + v.y + v.z + v.w;
    } else {
        #pragma unroll
        for (int i = 0; i < 4; ++i) if (idx + i < M) s += deg[idx + i];
    }
    #pragma unroll
    for (int off = 32; off > 0; off >>= 1) s += __shfl_down(s, off);
    __shared__ int ws[4];
    if ((t & 63) == 0) ws[t >> 6] = s;
    __syncthreads();
    if (t == 0) bsum[b] = ws[0] + ws[1] + ws[2] + ws[3];
}

// scan_partials fused in: every block wave-scans the <=64 bsum entries itself.
__global__ __launch_bounds__(256) void scan_blocks2_kernel(
    const int* __restrict__ deg, const int* __restrict__ bsum,
    int* __restrict__ rowptr, int* __restrict__ cur, int M, int E, int nB)
{
    const int b = blockIdx.x, t = threadIdx.x;
    __shared__ int sboff;
    if (t < 64) {
        const int v = (t < nB) ? bsum[t] : 0;
        int inc = v;
        #pragma unroll
        for (int off = 1; off < 64; off <<= 1) {
            const int u = __shfl_up(inc, off);
            if (t >= off) inc += u;
        }
        // exclusive prefix for block b = inclusive scan at lane b-1 (0 if b==0)
        const int prev = __shfl(inc, (b == 0) ? 0 : (b - 1));
        if (t == 0) sboff = (b == 0) ? 0 : prev;
    }
    const int idx = b * 1024 + t * 4;
    int4 d = make_int4(0, 0, 0, 0);
    if (idx + 3 < M) {
        d = *(const int4*)(deg + idx);
    } else {
        if (idx + 0 < M) d.x = deg[idx + 0];
        if (idx + 1 < M) d.y = deg[idx + 1];
        if (idx + 2 < M) d.z = deg[idx + 2];
        if (idx + 3 < M) d.w = deg[idx + 3];
    }
    const int tot = d.x + d.y + d.z + d.w;
    const int lane = t & 63, wid = t >> 6;
    int inc = tot;
    #pragma unroll
    for (int off = 1; off < 64; off <<= 1) {
        const int u = __shfl_up(inc, off);
        if (lane >= off) inc += u;
    }
    __shared__ int wsum[4];
    if (lane == 63) wsum[wid] = inc;
    __syncthreads();
    int woff = 0;
    #pragma unroll
    for (int w = 0; w < 4; ++w) if (w < wid) woff += wsum[w];
    int p = sboff + woff + (inc - tot);
    if (idx + 0 < M) { rowptr[idx + 0] = p; cur[idx + 0] = p; } p += d.x;
    if (idx + 1 < M) { rowptr[idx + 1] = p; cur[idx + 1] = p; } p += d.y;
    if (idx + 2 < M) { rowptr[idx + 2] = p; cur[idx + 2] = p; } p += d.z;
    if (idx + 3 < M) { rowptr[idx + 3] = p; cur[idx + 3] = p; }
    if (b == 0 && t == 0) rowptr[M] = E;
}

__global__ __launch_bounds__(256) void fill_kernel(
    const int* __restrict__ src, const int* __restrict__ dst,
    int* __restrict__ cur, int* __restrict__ srcs, int E)
{
    const int e = blockIdx.x * 256 + threadIdx.x;
    if (e >= E) return;
    const int p = atomicAdd(&cur[dst[e]], 1);
    srcs[p] = src[e];
}

// ---------------- gathers: 2 neighbors per wave ----------------
// d128: half-wave (32 lanes) covers a row at 8B/lane (4 elems).
__global__ __launch_bounds__(256) void gather_add_d128(
    const short* __restrict__ feat,    // M x 128 (unpadded)
    const int* __restrict__ rowptr, const int* __restrict__ srcs,
    short* __restrict__ outb, int M)   // M x S1
{
    const int row = blockIdx.x * 4 + (threadIdx.x >> 6);
    if (row >= M) return;
    const int lane = threadIdx.x & 63;
    const int half = lane >> 5;
    const int o = (lane & 31) * 4;     // elem offset, 4 elems (8B)
    float a0 = 0.f, a1 = 0.f, a2 = 0.f, a3 = 0.f;
    if (half == 0) {                   // self term once
        const uint2 u = *(const uint2*)(feat + (size_t)row * 128 + o);
        a0 = bflo(u.x); a1 = bfhi(u.x); a2 = bflo(u.y); a3 = bfhi(u.y);
    }
    const int jb = rowptr[row], je = rowptr[row + 1];
    int j = jb;
    for (; j + 8 <= je; j += 8) {      // 4 pairs per iter
        uint2 v[4];
        #pragma unroll
        for (int t = 0; t < 4; ++t) {
            const int s = srcs[j + 2 * t + half];
            v[t] = *(const uint2*)(feat + (size_t)s * 128 + o);
        }
        #pragma unroll
        for (int t = 0; t < 4; ++t) {
            a0 += bflo(v[t].x); a1 += bfhi(v[t].x);
            a2 += bflo(v[t].y); a3 += bfhi(v[t].y);
        }
    }
    for (; j + 2 <= je; j += 2) {
        const int s = srcs[j + half];
        const uint2 v = *(const uint2*)(feat + (size_t)s * 128 + o);
        a0 += bflo(v.x); a1 += bfhi(v.x); a2 += bflo(v.y); a3 += bfhi(v.y);
    }
    if (j < je && half == 0) {
        const uint2 v = *(const uint2*)(feat + (size_t)srcs[j] * 128 + o);
        a0 += bflo(v.x); a1 += bfhi(v.x); a2 += bflo(v.y); a3 += bfhi(v.y);
    }
    // merge halves
    a0 += __shfl_down(a0, 32);
    a1 += __shfl_down(a1, 32);
    a2 += __shfl_down(a2, 32);
    a3 += __shfl_down(a3, 32);
    if (half == 0) {
        uint2 up;
        up.x = (unsigned int)f2bf(a0) | ((unsigned int)f2bf(a1) << 16);
        up.y = (unsigned int)f2bf(a2) | ((unsigned int)f2bf(a3) << 16);
        *(uint2*)(outb + (size_t)row * S1 + o) = up;
    }
}

// d256: half-wave covers a row at 16B/lane (8 elems).
__global__ __launch_bounds__(256) void gather_add_d256(
    const short* __restrict__ feat,    // M x 256 (unpadded)
    const int* __restrict__ rowptr, const int* __restrict__ srcs,
    short* __restrict__ outb, int M)   // M x S2
{
    const int row = blockIdx.x * 4 + (threadIdx.x >> 6);
    if (row >= M) return;
    const int lane = threadIdx.x & 63;
    const int half = lane >> 5;
    const int o = (lane & 31) * 8;     // elem offset, 8 elems (16B)
    float a[8];
    #pragma unroll
    for (int k = 0; k < 8; ++k) a[k] = 0.f;
    if (half == 0) {                   // self term once
        const uint4 u = *(const uint4*)(feat + (size_t)row * 256 + o);
        a[0] = bflo(u.x); a[1] = bfhi(u.x); a[2] = bflo(u.y); a[3] = bfhi(u.y);
        a[4] = bflo(u.z); a[5] = bfhi(u.z); a[6] = bflo(u.w); a[7] = bfhi(u.w);
    }
    const int jb = rowptr[row], je = rowptr[row + 1];
    int j = jb;
    for (; j + 8 <= je; j += 8) {      // 4 pairs per iter
        uint4 v[4];
        #pragma unroll
        for (int t = 0; t < 4; ++t) {
            const int s = srcs[j + 2 * t + half];
            v[t] = *(const uint4*)(feat + (size_t)s * 256 + o);
        }
        #pragma unroll
        for (int t = 0; t < 4; ++t) {
            a[0] += bflo(v[t].x); a[1] += bfhi(v[t].x);
            a[2] += bflo(v[t].y); a[3] += bfhi(v[t].y);
            a[4] += bflo(v[t].z); a[5] += bfhi(v[t].z);
            a[6] += bflo(v[t].w); a[7] += bfhi(v[t].w);
        }
    }
    for (; j + 2 <= je; j += 2) {
        const int s = srcs[j + half];
        const uint4 v = *(const uint4*)(feat + (size_t)s * 256 + o);
        a[0] += bflo(v.x); a[1] += bfhi(v.x); a[2] += bflo(v.y); a[3] += bfhi(v.y);
        a[4] += bflo(v.z); a[5] += bfhi(v.z); a[6] += bflo(v.w); a[7] += bfhi(v.w);
    }
    if (j < je && half == 0) {
        const uint4 v = *(const uint4*)(feat + (size_t)srcs[j] * 256 + o);
        a[0] += bflo(v.x); a[1] += bfhi(v.x); a[2] += bflo(v.y); a[3] += bfhi(v.y);
        a[4] += bflo(v.z); a[5] += bfhi(v.z); a[6] += bflo(v.w); a[7] += bfhi(v.w);
    }
    #pragma unroll
    for (int k = 0; k < 8; ++k) a[k] += __shfl_down(a[k], 32);
    if (half == 0) {
        uint4 up;
        up.x = (unsigned int)f2bf(a[0]) | ((unsigned int)f2bf(a[1]) << 16);
        up.y = (unsigned int)f2bf(a[2]) | ((unsigned int)f2bf(a[3]) << 16);
        up.z = (unsigned int)f2bf(a[4]) | ((unsigned int)f2bf(a[5]) << 16);
        up.w = (unsigned int)f2bf(a[6]) | ((unsigned int)f2bf(a[7]) << 16);
        *(uint4*)(outb + (size_t)row * S2 + o) = up;
    }
}

// ---------------- layer1: h1 = relu(relu(h1in@w1+b1)@w2+b2) ----------------
__global__ __launch_bounds__(256) void layer1_fused(
    const short* __restrict__ h1in,   // M x S1 (payload 128)
    const short* __restrict__ w1t,    // 256 x S1 (payload 128)
    const float* __restrict__ b1,
    const short* __restrict__ w2t,    // 256 x S2 (payload 256)
    const float* __restrict__ b2,
    short* __restrict__ h1,           // M x 256 (unpadded)
    int M)
{
    __shared__ short sT[64 * S2];
    const int tid  = threadIdx.x;
    const int lane = tid & 63;
    const int wid  = tid >> 6;
    const int r16  = lane & 15;
    const int q    = lane >> 4;
    const int tm   = blockIdx.x * 64;
    const int wn   = wid * 64;

    f32x4 acc[4][4];
    #pragma unroll
    for (int i = 0; i < 4; ++i)
        #pragma unroll
        for (int j = 0; j < 4; ++j)
            acc[i][j] = (f32x4)0.f;

    // ---- GEMM1: t1 = relu(h1in @ w1 + b1), K = 128 ----
    const short* Abase = h1in + (size_t)tm * S1;
    #pragma unroll
    for (int k0 = 0; k0 < 128; k0 += 32) {
        bf16x8 af[4], bfr[4];
        #pragma unroll
        for (int i = 0; i < 4; ++i)
            af[i] = *(const bf16x8*)(Abase + (size_t)(i * 16 + r16) * S1 + k0 + q * 8);
        #pragma unroll
        for (int j = 0; j < 4; ++j)
            bfr[j] = *(const bf16x8*)(w1t + (size_t)(wn + j * 16 + r16) * S1 + k0 + q * 8);
        #pragma unroll
        for (int i = 0; i < 4; ++i)
            #pragma unroll
            for (int j = 0; j < 4; ++j)
                acc[i][j] = __builtin_amdgcn_mfma_f32_16x16x32_bf16(af[i], bfr[j], acc[i][j], 0, 0, 0);
    }

    // epilogue1 -> sT  (row = i*16 + q*4 + r, col = wn + j*16 + r16)
    #pragma unroll
    for (int j = 0; j < 4; ++j) {
        const int col = wn + j * 16 + r16;
        const float bj = b1[col];
        #pragma unroll
        for (int i = 0; i < 4; ++i)
            #pragma unroll
            for (int r = 0; r < 4; ++r) {
                float v = fmaxf(acc[i][j][r] + bj, 0.f);
                sT[(i * 16 + q * 4 + r) * S2 + col] = (short)f2bf(v);
            }
    }
    __syncthreads();

    // ---- GEMM2: h1 = relu(t1 @ w2 + b2), K = 256, A from LDS ----
    #pragma unroll
    for (int i = 0; i < 4; ++i)
        #pragma unroll
        for (int j = 0; j < 4; ++j)
            acc[i][j] = (f32x4)0.f;

    #pragma unroll
    for (int k0 = 0; k0 < 256; k0 += 32) {
        bf16x8 af[4], bfr[4];
        #pragma unroll
        for (int i = 0; i < 4; ++i)
            af[i] = *(const bf16x8*)(&sT[(i * 16 + r16) * S2 + k0 + q * 8]);
        #pragma unroll
        for (int j = 0; j < 4; ++j)
            bfr[j] = *(const bf16x8*)(w2t + (size_t)(wn + j * 16 + r16) * S2 + k0 + q * 8);
        #pragma unroll
        for (int i = 0; i < 4; ++i)
            #pragma unroll
            for (int j = 0; j < 4; ++j)
                acc[i][j] = __builtin_amdgcn_mfma_f32_16x16x32_bf16(af[i], bfr[j], acc[i][j], 0, 0, 0);
    }
    __syncthreads();   // all waves done reading sT

    // epilogue2 -> sT (reused as h1 tile), then coalesced store
    #pragma unroll
    for (int j = 0; j < 4; ++j) {
        const int col = wn + j * 16 + r16;
        const float bj = b2[col];
        #pragma unroll
        for (int i = 0; i < 4; ++i)
            #pragma unroll
            for (int r = 0; r < 4; ++r) {
                float v = fmaxf(acc[i][j][r] + bj, 0.f);
                sT[(i * 16 + q * 4 + r) * S2 + col] = (short)f2bf(v);
            }
    }
    __syncthreads();

    #pragma unroll
    for (int c = 0; c < 8; ++c) {
        const int idx = tid + c * 256;
        const int row = idx >> 5;
        const int ch  = idx & 31;
        const int rg  = tm + row;
        if (rg < M) {
            const uint4 v = *(const uint4*)(&sT[row * S2 + ch * 8]);
            *(uint4*)(h1 + (size_t)rg * 256 + ch * 8) = v;
        }
    }
}

// ---------------- layer2: out = log_softmax(relu(h2in@w3+b3) @ w4 + b4) ----------------
__global__ __launch_bounds__(256) void layer2_fused(
    const short* __restrict__ h2in,   // M x S2 (payload 256)
    const short* __restrict__ w3t,    // 256 x S2
    const float* __restrict__ b3,
    const float* __restrict__ w4,     // 256 x 2 fp32
    const float* __restrict__ b4,
    float* __restrict__ out,          // M x 2
    int M)
{
    __shared__ short sT[64 * S2];
    const int tid  = threadIdx.x;
    const int lane = tid & 63;
    const int wid  = tid >> 6;
    const int r16  = lane & 15;
    const int q    = lane >> 4;
    const int tm   = blockIdx.x * 64;
    const int wn   = wid * 64;

    f32x4 acc[4][4];
    #pragma unroll
    for (int i = 0; i < 4; ++i)
        #pragma unroll
        for (int j = 0; j < 4; ++j)
            acc[i][j] = (f32x4)0.f;

    const short* Abase = h2in + (size_t)tm * S2;
    #pragma unroll
    for (int k0 = 0; k0 < 256; k0 += 32) {
        bf16x8 af[4], bfr[4];
        #pragma unroll
        for (int i = 0; i < 4; ++i)
            af[i] = *(const bf16x8*)(Abase + (size_t)(i * 16 + r16) * S2 + k0 + q * 8);
        #pragma unroll
        for (int j = 0; j < 4; ++j)
            bfr[j] = *(const bf16x8*)(w3t + (size_t)(wn + j * 16 + r16) * S2 + k0 + q * 8);
        #pragma unroll
        for (int i = 0; i < 4; ++i)
            #pragma unroll
            for (int j = 0; j < 4; ++j)
                acc[i][j] = __builtin_amdgcn_mfma_f32_16x16x32_bf16(af[i], bfr[j], acc[i][j], 0, 0, 0);
    }

    // epilogue -> sT (t2 tile, bf16 + relu + bias)
    #pragma unroll
    for (int j = 0; j < 4; ++j) {
        const int col = wn + j * 16 + r16;
        const float bj = b3[col];
        #pragma unroll
        for (int i = 0; i < 4; ++i)
            #pragma unroll
            for (int r = 0; r < 4; ++r) {
                float v = fmaxf(acc[i][j][r] + bj, 0.f);
                sT[(i * 16 + q * 4 + r) * S2 + col] = (short)f2bf(v);
            }
    }
    __syncthreads();

    // head: 4 threads per row, 64 k each; shuffle-reduce width 4
    const int row = tid >> 2;
    const int qd  = tid & 3;
    const short* tp = &sT[row * S2 + qd * 64];
    const float* w4p = w4 + qd * 128;
    float s0 = 0.f, s1 = 0.f;
    #pragma unroll 8
    for (int k = 0; k < 64; ++k) {
        const float a = bf2f((unsigned short)tp[k]);
        const float2 w = *(const float2*)(w4p + 2 * k);
        s0 = fmaf(a, w.x, s0);
        s1 = fmaf(a, w.y, s1);
    }
    s0 += __shfl_down(s0, 2, 4);  s1 += __shfl_down(s1, 2, 4);
    s0 += __shfl_down(s0, 1, 4);  s1 += __shfl_down(s1, 1, 4);
    if (qd == 0) {
        const int rg = tm + row;
        if (rg < M) {
            s0 += b4[0];
            s1 += b4[1];
            const float m = fmaxf(s0, s1);
            const float l = logf(__expf(s0 - m) + __expf(s1 - m));
            float2 o;
            o.x = s0 - m - l;
            o.y = s1 - m - l;
            *(float2*)(out + (size_t)rg * 2) = o;
        }
    }
}

extern "C" void kernel_launch(void* const* d_in, const int* in_sizes, int n_in,
                              void* d_out, int out_size, void* d_ws, size_t ws_size,
                              hipStream_t stream)
{
    const float* x  = (const float*)d_in[0];
    const int*   ei = (const int*)d_in[1];
    const float* w1 = (const float*)d_in[2];
    const float* b1 = (const float*)d_in[3];
    const float* w2 = (const float*)d_in[4];
    const float* b2 = (const float*)d_in[5];
    const float* w3 = (const float*)d_in[6];
    const float* b3 = (const float*)d_in[7];
    const float* w4 = (const float*)d_in[8];
    const float* b4 = (const float*)d_in[9];

    const int DIN = 128, DH = 256;
    const int M = in_sizes[0] / DIN;   // 50000
    const int E = in_sizes[1] / 2;     // 600000
    const int* src = ei;
    const int* dst = ei + E;
    const int nB = (M + 1023) / 1024;  // <= 64

    // -------- workspace layout --------
    int* deg    = (int*)d_ws;
    int* cur    = deg + M;
    int* rowptr = cur + M;
    int* bsum   = rowptr + (M + 1);
    int* srcs   = bsum + 64;
    size_t off = ((size_t)(3 * M + 1 + 64 + E) * sizeof(int) + 255) & ~(size_t)255;
    short* x_bf = (short*)((char*)d_ws + off);  off += (size_t)M * DIN * 2;   // M x 128
    off = (off + 255) & ~(size_t)255;
    short* h1in = (short*)((char*)d_ws + off);  off += (size_t)M * S1 * 2;    // M x 136
    off = (off + 255) & ~(size_t)255;
    short* h1   = (short*)((char*)d_ws + off);  off += (size_t)M * DH * 2;    // M x 256
    off = (off + 255) & ~(size_t)255;
    short* h2in = (short*)((char*)d_ws + off);  off += (size_t)M * S2 * 2;    // M x 264
    off = (off + 255) & ~(size_t)255;
    short* w1t  = (short*)((char*)d_ws + off);  off += (size_t)DH * S1 * 2;   // 256 x 136
    off = (off + 255) & ~(size_t)255;
    short* w2t  = (short*)((char*)d_ws + off);  off += (size_t)DH * S2 * 2;   // 256 x 264
    off = (off + 255) & ~(size_t)255;
    short* w3t  = (short*)((char*)d_ws + off);  off += (size_t)DH * S2 * 2;   // 256 x 264

    // -------- prep (zero deg | cvt x | transpose weights) --------
    const int zB = nB;                       // 49 blocks zero deg
    const int cB = (M * 32 + 255) / 256;     // cvt blocks (M*128/4 elems, 256 thr)
    prep_kernel<<<zB + cB + 192, 256, 0, stream>>>(
        x, x_bf, w1, w2, w3, w1t, w2t, w3t, deg, M, zB, cB);

    // -------- CSR build --------
    degree_kernel<<<(E + 255) / 256, 256, 0, stream>>>(dst, deg, E);
    block_sum_kernel<<<nB, 256, 0, stream>>>(deg, bsum, M);
    scan_blocks2_kernel<<<nB, 256, 0, stream>>>(deg, bsum, rowptr, cur, M, E, nB);
    fill_kernel<<<(E + 255) / 256, 256, 0, stream>>>(src, dst, cur, srcs, E);

    const int nblk = (M + 63) / 64;

    // -------- layer 1 --------
    gather_add_d128<<<(M + 3) / 4, 256, 0, stream>>>(x_bf, rowptr, srcs, h1in, M);
    layer1_fused<<<nblk, 256, 0, stream>>>(h1in, w1t, b1, w2t, b2, h1, M);

    // -------- layer 2 --------
    gather_add_d256<<<(M + 3) / 4, 256, 0, stream>>>(h1, rowptr, srcs, h2in, M);
    layer2_fused<<<nblk, 256, 0, stream>>>(h2in, w3t, b3, w4, b4, (float*)d_out, M);
}